// Round 3
// baseline (958.268 us; speedup 1.0000x reference)
//
#include <hip/hip_runtime.h>
#include <hip/hip_bf16.h>

#define N_NODES 100000
#define N_EDGES 500000
#define H 128
#define EPS 1e-5f

typedef __attribute__((ext_vector_type(8))) short bf16x8;
typedef __attribute__((ext_vector_type(4))) float f32x4;

__device__ __forceinline__ unsigned short f2bf(float f) {
  unsigned int u = __builtin_bit_cast(unsigned int, f);
  u += 0x7FFFu + ((u >> 16) & 1u);
  return (unsigned short)(u >> 16);
}
__device__ __forceinline__ float bf2f(unsigned short u) {
  return __builtin_bit_cast(float, (unsigned)u << 16);
}

// XOR-swizzled LDS layout for a 128x128 bf16 tile (linear 32KB).
// (r,k) -> ushort idx r*128 + (k ^ ((r&7)<<3)); 16B chunks stay intact.
__device__ __forceinline__ int swz(int r, int k) {
  return r * 128 + (k ^ ((r & 7) << 3));
}

union PK8 { unsigned short u[8]; uint4 q; };

#define GLDS16(g, l)                                                        \
  __builtin_amdgcn_global_load_lds(                                         \
      (const __attribute__((address_space(1))) void*)(g),                   \
      (__attribute__((address_space(3))) void*)(l), 16, 0, 0)

// ---- A staging ----

// f32 global -> bf16 LDS (one 64-col half-row per thread). src==nullptr -> zeros.
__device__ __forceinline__ void stage_a_half(unsigned short* Abuf, int r, int k0,
                                             const float* src) {
  #pragma unroll
  for (int j = 0; j < 8; ++j) {
    PK8 pk;
    if (src) {
      float4 v0 = *(const float4*)(src + j * 8);
      float4 v1 = *(const float4*)(src + j * 8 + 4);
      pk.u[0] = f2bf(v0.x); pk.u[1] = f2bf(v0.y);
      pk.u[2] = f2bf(v0.z); pk.u[3] = f2bf(v0.w);
      pk.u[4] = f2bf(v1.x); pk.u[5] = f2bf(v1.y);
      pk.u[6] = f2bf(v1.z); pk.u[7] = f2bf(v1.w);
    } else {
      #pragma unroll
      for (int q = 0; q < 8; ++q) pk.u[q] = 0;
    }
    *(uint4*)&Abuf[swz(r, k0 + j * 8)] = pk.q;
  }
}

// bf16 gather rows -> swizzled Abuf via global_load_lds.
// Linear LDS dest (wave-uniform base + lane*16); source chunk pre-swizzled:
// LDS chunk c holds source chunk c ^ (r&7)  (involution of swz()).
__device__ __forceinline__ void stage_gather(const unsigned short* xb,
                                             const int* __restrict__ idx, long e0,
                                             unsigned short* Abuf) {
  const int t = threadIdx.x;
  const int c = t & 15;
  #pragma unroll
  for (int j = 0; j < 8; ++j) {
    const int r = j * 16 + (t >> 4);
    long e = e0 + r;
    if (e > N_EDGES - 1) e = N_EDGES - 1;
    const long node = idx[e];
    const unsigned short* src = xb + node * H + ((c ^ (r & 7)) * 8);
    GLDS16(src, (char*)Abuf + j * 4096 + t * 16);
  }
}

// bf16 sequential rows -> swizzled Abuf via global_load_lds.
__device__ __forceinline__ void stage_seq(const unsigned short* xb, long n0,
                                          unsigned short* Abuf) {
  const int t = threadIdx.x;
  const int c = t & 15;
  #pragma unroll
  for (int j = 0; j < 8; ++j) {
    const int r = j * 16 + (t >> 4);
    long n = n0 + r;
    if (n > N_NODES - 1) n = N_NODES - 1;
    const unsigned short* src = xb + n * H + ((c ^ (r & 7)) * 8);
    GLDS16(src, (char*)Abuf + j * 4096 + t * 16);
  }
}

// ---- GEMM: [32 x 128] += A(LDS) @ B(global WT[n][k], L2-hot) ----
__device__ __forceinline__ void gemm128_gw(const unsigned short* Abuf,
                                           const unsigned short* __restrict__ wt,
                                           int row_base, int m0, int kq,
                                           f32x4 acc[2][8]) {
  #pragma unroll
  for (int kk = 0; kk < 4; ++kk) {
    const int k0 = kk * 32 + kq * 8;
    bf16x8 a0 = *(const bf16x8*)&Abuf[swz(row_base + m0, k0)];
    bf16x8 a1 = *(const bf16x8*)&Abuf[swz(row_base + 16 + m0, k0)];
    #pragma unroll
    for (int tc = 0; tc < 8; ++tc) {
      bf16x8 b = *(const bf16x8*)&wt[(tc * 16 + m0) * H + k0];
      acc[0][tc] = __builtin_amdgcn_mfma_f32_16x16x32_bf16(a0, b, acc[0][tc], 0, 0, 0);
      acc[1][tc] = __builtin_amdgcn_mfma_f32_16x16x32_bf16(a1, b, acc[1][tc], 0, 0, 0);
    }
  }
}

// C-layout: col = tc*16 + (lane&15), row = tr*16 + (lane>>4)*4 + i
__device__ __forceinline__ void write_hidden_relu(unsigned short* Abuf, f32x4 acc[2][8],
                                                  const float* __restrict__ bias,
                                                  int row_base, int m0, int kq) {
  #pragma unroll
  for (int tc = 0; tc < 8; ++tc) {
    const int col = tc * 16 + m0;
    const float b = bias[col];
    #pragma unroll
    for (int tr = 0; tr < 2; ++tr)
      #pragma unroll
      for (int i = 0; i < 4; ++i)
        Abuf[swz(row_base + tr * 16 + kq * 4 + i, col)] =
            f2bf(fmaxf(acc[tr][tc][i] + b, 0.0f));
  }
}

__device__ __forceinline__ void zero_acc(f32x4 acc[2][8]) {
  #pragma unroll
  for (int a = 0; a < 2; ++a)
    #pragma unroll
    for (int b = 0; b < 8; ++b)
      acc[a][b] = (f32x4){0.f, 0.f, 0.f, 0.f};
}

__device__ __forceinline__ void ln_stats(const f32x4 acc[2][8], float mu[2][4],
                                         float rv[2][4]) {
  #pragma unroll
  for (int tr = 0; tr < 2; ++tr) {
    float s[4] = {0, 0, 0, 0}, ss[4] = {0, 0, 0, 0};
    #pragma unroll
    for (int tc = 0; tc < 8; ++tc)
      #pragma unroll
      for (int i = 0; i < 4; ++i) {
        const float v = acc[tr][tc][i];
        s[i] += v;
        ss[i] += v * v;
      }
    #pragma unroll
    for (int off = 1; off < 16; off <<= 1) {
      #pragma unroll
      for (int i = 0; i < 4; ++i) {
        s[i] += __shfl_xor(s[i], off);
        ss[i] += __shfl_xor(ss[i], off);
      }
    }
    #pragma unroll
    for (int i = 0; i < 4; ++i) {
      const float m = s[i] * (1.0f / 128.0f);
      const float var = ss[i] * (1.0f / 128.0f) - m * m;
      mu[tr][i] = m;
      rv[tr][i] = rsqrtf(var + EPS);
    }
  }
}

// ---------------- prep kernels ----------------

__global__ void xprep_kernel(const float* __restrict__ x,
                             unsigned short* __restrict__ xb) {
  const long i = (long)blockIdx.x * 256 + threadIdx.x;
  const long base = i * 8;
  if (base < (long)N_NODES * H) {
    float4 v0 = *(const float4*)(x + base);
    float4 v1 = *(const float4*)(x + base + 4);
    PK8 pk;
    pk.u[0] = f2bf(v0.x); pk.u[1] = f2bf(v0.y);
    pk.u[2] = f2bf(v0.z); pk.u[3] = f2bf(v0.w);
    pk.u[4] = f2bf(v1.x); pk.u[5] = f2bf(v1.y);
    pk.u[6] = f2bf(v1.z); pk.u[7] = f2bf(v1.w);
    *(uint4*)(xb + base) = pk.q;
  }
}

struct WSrc { const float* p[9]; };

// WT layout: wimg[m][n*128 + k] = W_m[k][n]  (bf16)
__global__ void wprep_kernel(WSrc wsrc, unsigned short* __restrict__ wimg) {
  const int id = blockIdx.x * 256 + threadIdx.x;  // 9*16384 = 147456
  const int m = id >> 14;
  const int r = id & 16383;
  const int n = r & 127;  // consecutive threads -> consecutive n (coalesced read)
  const int k = r >> 7;
  wimg[m * 16384 + n * 128 + k] = f2bf(wsrc.p[m][k * 128 + n]);
}

// ---------------- CSR build ----------------

__global__ void hist_kernel(const int* __restrict__ ridx, unsigned* __restrict__ cnt) {
  const int e = blockIdx.x * 256 + threadIdx.x;
  if (e < N_EDGES) atomicAdd(&cnt[ridx[e]], 1u);
}

__global__ void scan1_kernel(const unsigned* __restrict__ cnt,
                             unsigned* __restrict__ offs,
                             unsigned* __restrict__ part) {
  __shared__ unsigned sh[256];
  const int t = threadIdx.x;
  const int base = blockIdx.x * 1024 + t * 4;
  unsigned v[4];
  #pragma unroll
  for (int i = 0; i < 4; ++i) v[i] = (base + i < N_NODES) ? cnt[base + i] : 0u;
  unsigned pre[4];
  pre[0] = 0; pre[1] = v[0]; pre[2] = v[0] + v[1]; pre[3] = pre[2] + v[2];
  const unsigned tot = pre[3] + v[3];
  sh[t] = tot;
  __syncthreads();
  for (int d = 1; d < 256; d <<= 1) {
    const unsigned u_ = (t >= d) ? sh[t - d] : 0u;
    __syncthreads();
    sh[t] += u_;
    __syncthreads();
  }
  const unsigned excl = sh[t] - tot;
  #pragma unroll
  for (int i = 0; i < 4; ++i)
    if (base + i < N_NODES) offs[base + i] = excl + pre[i];
  if (t == 255) part[blockIdx.x] = sh[255];
}

__global__ void scan2_kernel(unsigned* __restrict__ part, int n) {
  __shared__ unsigned sh[128];
  const int t = threadIdx.x;
  const unsigned v = (t < n) ? part[t] : 0u;
  sh[t] = v;
  __syncthreads();
  for (int d = 1; d < 128; d <<= 1) {
    const unsigned u_ = (t >= d) ? sh[t - d] : 0u;
    __syncthreads();
    sh[t] += u_;
    __syncthreads();
  }
  if (t < n) part[t] = sh[t] - v;
}

__global__ void scan3_kernel(unsigned* __restrict__ offs,
                             const unsigned* __restrict__ part,
                             unsigned* __restrict__ cursor) {
  const int i = blockIdx.x * 256 + threadIdx.x;
  if (i < N_NODES) {
    const unsigned o = offs[i] + part[i >> 10];
    offs[i] = o;
    cursor[i] = o;
  }
  if (i == 0) offs[N_NODES] = N_EDGES;
}

__global__ void scatter_kernel(const int* __restrict__ ridx,
                               unsigned* __restrict__ cursor,
                               unsigned* __restrict__ eord) {
  const int e = blockIdx.x * 256 + threadIdx.x;
  if (e < N_EDGES) {
    const unsigned p = atomicAdd(&cursor[ridx[e]], 1u);
    eord[p] = (unsigned)e;
  }
}

// ---------------- main kernels ----------------

__global__ __launch_bounds__(256, 4) void edge_kernel(
    const unsigned short* __restrict__ xb, const float* __restrict__ edge_attr,
    const int* __restrict__ eidx, const unsigned short* __restrict__ wimg,
    const float* __restrict__ eb1, const float* __restrict__ eb2,
    const float* __restrict__ eb3,
    const float* __restrict__ eg, const float* __restrict__ ebeta,
    float* __restrict__ out_e, unsigned short* __restrict__ enew) {
  __shared__ unsigned short Abuf[128 * 128];

  const int t = threadIdx.x;
  const int lane = t & 63;
  const int wave = t >> 6;
  const int row_base = wave * 32;
  const int m0 = lane & 15;
  const int kq = lane >> 4;
  const long e0 = (long)blockIdx.x * 128;
  const int* sidx = eidx;
  const int* ridx = eidx + N_EDGES;

  const int sr = t >> 1;
  const int sk0 = (t & 1) * 64;

  f32x4 acc[2][8];
  zero_acc(acc);

  // ---- Layer 1, p0: x[sidx] @ W1a ----
  stage_gather(xb, sidx, e0, Abuf);
  __syncthreads();
  gemm128_gw(Abuf, wimg + 0L * 16384, row_base, m0, kq, acc);
  __syncthreads();

  // ---- Layer 1, p1: x[ridx] @ W1b ----
  stage_gather(xb, ridx, e0, Abuf);
  __syncthreads();
  gemm128_gw(Abuf, wimg + 1L * 16384, row_base, m0, kq, acc);
  __syncthreads();

  // ---- Layer 1, p2: edge_attr @ W1c ----
  {
    const long se = e0 + sr;
    stage_a_half(Abuf, sr, sk0,
                 (se < N_EDGES) ? edge_attr + se * (long)H + sk0 : nullptr);
  }
  __syncthreads();
  gemm128_gw(Abuf, wimg + 2L * 16384, row_base, m0, kq, acc);

  // ---- Layer 2 ----
  __syncthreads();
  write_hidden_relu(Abuf, acc, eb1, row_base, m0, kq);
  zero_acc(acc);
  __syncthreads();
  gemm128_gw(Abuf, wimg + 3L * 16384, row_base, m0, kq, acc);

  // ---- Layer 3 ----
  __syncthreads();
  write_hidden_relu(Abuf, acc, eb2, row_base, m0, kq);
  zero_acc(acc);
  __syncthreads();
  gemm128_gw(Abuf, wimg + 4L * 16384, row_base, m0, kq, acc);

  // ---- Epilogue: +b3, LN -> y bf16 into Abuf -> vectorized global I/O ----
  float gm[8], bt[8];
  #pragma unroll
  for (int tc = 0; tc < 8; ++tc) {
    const int col = tc * 16 + m0;
    const float b3 = eb3[col];
    gm[tc] = eg[col];
    bt[tc] = ebeta[col];
    #pragma unroll
    for (int tr = 0; tr < 2; ++tr)
      #pragma unroll
      for (int i = 0; i < 4; ++i)
        acc[tr][tc][i] += b3;
  }
  float mu[2][4], rv[2][4];
  ln_stats(acc, mu, rv);

  __syncthreads();
  #pragma unroll
  for (int tc = 0; tc < 8; ++tc) {
    const int col = tc * 16 + m0;
    #pragma unroll
    for (int tr = 0; tr < 2; ++tr)
      #pragma unroll
      for (int i = 0; i < 4; ++i) {
        const float y = (acc[tr][tc][i] - mu[tr][i]) * rv[tr][i] * gm[tc] + bt[tc];
        Abuf[swz(row_base + tr * 16 + kq * 4 + i, col)] = f2bf(y);
      }
  }
  __syncthreads();
  {
    const long e = e0 + sr;
    if (e < N_EDGES) {
      const float* ea = edge_attr + e * (long)H + sk0;
      float* oe = out_e + e * (long)H + sk0;
      unsigned short* en = enew + e * (long)H + sk0;
      #pragma unroll
      for (int c2 = 0; c2 < 8; ++c2) {
        uint4 q = *(const uint4*)&Abuf[swz(sr, sk0 + c2 * 8)];
        *(uint4*)(en + c2 * 8) = q;
        const unsigned short* pu = (const unsigned short*)&q;
        float4 a0 = *(const float4*)(ea + c2 * 8);
        float4 a1 = *(const float4*)(ea + c2 * 8 + 4);
        float4 o0, o1;
        o0.x = a0.x + bf2f(pu[0]); o0.y = a0.y + bf2f(pu[1]);
        o0.z = a0.z + bf2f(pu[2]); o0.w = a0.w + bf2f(pu[3]);
        o1.x = a1.x + bf2f(pu[4]); o1.y = a1.y + bf2f(pu[5]);
        o1.z = a1.z + bf2f(pu[6]); o1.w = a1.w + bf2f(pu[7]);
        *(float4*)(oe + c2 * 8) = o0;
        *(float4*)(oe + c2 * 8 + 4) = o1;
      }
    }
  }
}

__global__ __launch_bounds__(256, 2) void node_kernel(
    const unsigned short* __restrict__ xb, const float* __restrict__ x,
    const unsigned short* __restrict__ enew,
    const unsigned* __restrict__ offs, const unsigned* __restrict__ eord,
    const unsigned short* __restrict__ wimg,
    const float* __restrict__ nb1, const float* __restrict__ nb2,
    const float* __restrict__ nb3,
    const float* __restrict__ ng, const float* __restrict__ nbeta,
    float* __restrict__ out_x) {
  __shared__ unsigned short Abuf[128 * 128];

  const int t = threadIdx.x;
  const int lane = t & 63;
  const int wave = t >> 6;
  const int row_base = wave * 32;
  const int m0 = lane & 15;
  const int kq = lane >> 4;
  const long n0 = (long)blockIdx.x * 128;

  const int sr = t >> 1;
  const int sk0 = (t & 1) * 64;
  const long sn = n0 + sr;
  const bool svalid = (sn < N_NODES);

  f32x4 acc[2][8];
  zero_acc(acc);

  // ---- Layer 1, p0: x @ W1a ----
  stage_seq(xb, n0, Abuf);
  __syncthreads();
  gemm128_gw(Abuf, wimg + 5L * 16384, row_base, m0, kq, acc);
  __syncthreads();

  // ---- Layer 1, p1: agg @ W1b (CSR gather-sum of e_new) ----
  {
    float av[64];
    #pragma unroll
    for (int i = 0; i < 64; ++i) av[i] = 0.f;
    if (svalid) {
      const unsigned o0 = offs[sn], o1 = offs[sn + 1];
      for (unsigned u_ = o0; u_ < o1; ++u_) {
        const unsigned short* er = enew + (long)eord[u_] * H + sk0;
        #pragma unroll
        for (int j = 0; j < 8; ++j) {
          uint4 q = *(const uint4*)(er + j * 8);
          const unsigned short* pu = (const unsigned short*)&q;
          #pragma unroll
          for (int c = 0; c < 8; ++c)
            av[j * 8 + c] += bf2f(pu[c]);
        }
      }
    }
    #pragma unroll
    for (int j = 0; j < 8; ++j) {
      PK8 pk;
      #pragma unroll
      for (int c = 0; c < 8; ++c) pk.u[c] = f2bf(av[j * 8 + c]);
      *(uint4*)&Abuf[swz(sr, sk0 + j * 8)] = pk.q;
    }
  }
  __syncthreads();
  gemm128_gw(Abuf, wimg + 6L * 16384, row_base, m0, kq, acc);

  // ---- Layer 2 ----
  __syncthreads();
  write_hidden_relu(Abuf, acc, nb1, row_base, m0, kq);
  zero_acc(acc);
  __syncthreads();
  gemm128_gw(Abuf, wimg + 7L * 16384, row_base, m0, kq, acc);

  // ---- Layer 3 ----
  __syncthreads();
  write_hidden_relu(Abuf, acc, nb2, row_base, m0, kq);
  zero_acc(acc);
  __syncthreads();
  gemm128_gw(Abuf, wimg + 8L * 16384, row_base, m0, kq, acc);

  // ---- Epilogue ----
  float gm[8], bt[8];
  #pragma unroll
  for (int tc = 0; tc < 8; ++tc) {
    const int col = tc * 16 + m0;
    const float b3 = nb3[col];
    gm[tc] = ng[col];
    bt[tc] = nbeta[col];
    #pragma unroll
    for (int tr = 0; tr < 2; ++tr)
      #pragma unroll
      for (int i = 0; i < 4; ++i)
        acc[tr][tc][i] += b3;
  }
  float mu[2][4], rv[2][4];
  ln_stats(acc, mu, rv);

  __syncthreads();
  #pragma unroll
  for (int tc = 0; tc < 8; ++tc) {
    const int col = tc * 16 + m0;
    #pragma unroll
    for (int tr = 0; tr < 2; ++tr)
      #pragma unroll
      for (int i = 0; i < 4; ++i) {
        const float y = (acc[tr][tc][i] - mu[tr][i]) * rv[tr][i] * gm[tc] + bt[tc];
        Abuf[swz(row_base + tr * 16 + kq * 4 + i, col)] = f2bf(y);
      }
  }
  __syncthreads();
  if (svalid) {
    const float* xr = x + sn * (long)H + sk0;
    float* ox = out_x + sn * (long)H + sk0;
    #pragma unroll
    for (int c2 = 0; c2 < 8; ++c2) {
      uint4 q = *(const uint4*)&Abuf[swz(sr, sk0 + c2 * 8)];
      const unsigned short* pu = (const unsigned short*)&q;
      float4 a0 = *(const float4*)(xr + c2 * 8);
      float4 a1 = *(const float4*)(xr + c2 * 8 + 4);
      float4 o0, o1;
      o0.x = a0.x + bf2f(pu[0]); o0.y = a0.y + bf2f(pu[1]);
      o0.z = a0.z + bf2f(pu[2]); o0.w = a0.w + bf2f(pu[3]);
      o1.x = a1.x + bf2f(pu[4]); o1.y = a1.y + bf2f(pu[5]);
      o1.z = a1.z + bf2f(pu[6]); o1.w = a1.w + bf2f(pu[7]);
      *(float4*)(ox + c2 * 8) = o0;
      *(float4*)(ox + c2 * 8 + 4) = o1;
    }
  }
}

extern "C" void kernel_launch(void* const* d_in, const int* in_sizes, int n_in,
                              void* d_out, int out_size, void* d_ws, size_t ws_size,
                              hipStream_t stream) {
  (void)in_sizes; (void)n_in; (void)out_size; (void)ws_size;
  const float* x         = (const float*)d_in[0];
  const float* edge_attr = (const float*)d_in[1];
  const int*   eidx      = (const int*)d_in[2];
  const float* eW1 = (const float*)d_in[3];
  const float* eb1 = (const float*)d_in[4];
  const float* eW2 = (const float*)d_in[5];
  const float* eb2 = (const float*)d_in[6];
  const float* eW3 = (const float*)d_in[7];
  const float* eb3 = (const float*)d_in[8];
  const float* eg  = (const float*)d_in[9];
  const float* ebt = (const float*)d_in[10];
  const float* nW1 = (const float*)d_in[11];
  const float* nb1 = (const float*)d_in[12];
  const float* nW2 = (const float*)d_in[13];
  const float* nb2 = (const float*)d_in[14];
  const float* nW3 = (const float*)d_in[15];
  const float* nb3 = (const float*)d_in[16];
  const float* ng  = (const float*)d_in[17];
  const float* nbt = (const float*)d_in[18];

  float* out_x = (float*)d_out;                        // N_NODES*H
  float* out_e = (float*)d_out + (size_t)N_NODES * H;  // N_EDGES*H

  // ws layout (bytes)
  char* w = (char*)d_ws;
  unsigned short* enew = (unsigned short*)(w + 0);            // 128,000,000
  unsigned short* xb   = (unsigned short*)(w + 128000000);    //  25,600,000
  unsigned short* wimg = (unsigned short*)(w + 153600000);    //     294,912
  unsigned* offs   = (unsigned*)(w + 153894912);              //     400,128
  unsigned* cnt    = (unsigned*)(w + 154295040);              //     400,128
  unsigned* cursor = (unsigned*)(w + 154695168);              //     400,128
  unsigned* part   = (unsigned*)(w + 155095296);              //       1,024
  unsigned* eord   = (unsigned*)(w + 155096320);              //   2,000,000
  // total ~157.1 MB

  const int* ridx = eidx + N_EDGES;

  hipMemsetAsync(cnt, 0, (size_t)N_NODES * sizeof(unsigned), stream);

  WSrc wsrc;
  wsrc.p[0] = eW1;
  wsrc.p[1] = eW1 + 16384;
  wsrc.p[2] = eW1 + 32768;
  wsrc.p[3] = eW2;
  wsrc.p[4] = eW3;
  wsrc.p[5] = nW1;
  wsrc.p[6] = nW1 + 16384;
  wsrc.p[7] = nW2;
  wsrc.p[8] = nW3;

  xprep_kernel<<<(N_NODES * H / 8 + 255) / 256, 256, 0, stream>>>(x, xb);
  wprep_kernel<<<576, 256, 0, stream>>>(wsrc, wimg);

  hist_kernel<<<(N_EDGES + 255) / 256, 256, 0, stream>>>(ridx, cnt);
  scan1_kernel<<<(N_NODES + 1023) / 1024, 256, 0, stream>>>(cnt, offs, part);
  scan2_kernel<<<1, 128, 0, stream>>>(part, (N_NODES + 1023) / 1024);
  scan3_kernel<<<(N_NODES + 255) / 256, 256, 0, stream>>>(offs, part, cursor);
  scatter_kernel<<<(N_EDGES + 255) / 256, 256, 0, stream>>>(ridx, cursor, eord);

  const int eblocks = (N_EDGES + 127) / 128;  // 3907
  const int nblocks = (N_NODES + 127) / 128;  // 782
  edge_kernel<<<eblocks, 256, 0, stream>>>(xb, edge_attr, eidx, wimg, eb1, eb2, eb3,
                                           eg, ebt, out_e, enew);
  node_kernel<<<nblocks, 256, 0, stream>>>(xb, x, enew, offs, eord, wimg,
                                           nb1, nb2, nb3, ng, nbt, out_x);
}

// Round 4
// 459.014 us; speedup vs baseline: 2.0877x; 2.0877x over previous
//
#include <hip/hip_runtime.h>

#define N_NODES 100000
#define N_EDGES 500000
#define H 128
#define EPS 1e-5f

typedef __attribute__((ext_vector_type(8))) short bf16x8;
typedef __attribute__((ext_vector_type(4))) float f32x4;

__device__ __forceinline__ unsigned short f2bf(float f) {
  unsigned int u = __builtin_bit_cast(unsigned int, f);
  u += 0x7FFFu + ((u >> 16) & 1u);
  return (unsigned short)(u >> 16);
}
__device__ __forceinline__ float bf2f(unsigned short u) {
  return __builtin_bit_cast(float, (unsigned)u << 16);
}

// XOR-swizzled LDS layout for a 128x128 bf16 tile (32KB linear).
// (r,k) -> ushort idx r*128 + (k ^ ((r&7)<<3)); 16B chunks stay intact.
__device__ __forceinline__ int swz(int r, int k) {
  return r * 128 + (k ^ ((r & 7) << 3));
}

union PK8 { unsigned short u[8]; uint4 q; };

#define GLDS16(g, l)                                                        \
  __builtin_amdgcn_global_load_lds(                                         \
      (const __attribute__((address_space(1))) void*)(g),                   \
      (__attribute__((address_space(3))) void*)(l), 16, 0, 0)

// Copy a 32KB pre-swizzled weight image into LDS (512 threads x 16B x 4).
__device__ __forceinline__ void stage_w512(unsigned short* dst,
                                           const unsigned short* img) {
  const int t = threadIdx.x;
  #pragma unroll
  for (int j = 0; j < 4; ++j)
    GLDS16((const char*)img + j * 8192 + t * 16, (char*)dst + j * 8192 + t * 16);
}

// acc[8] += A(regs)[16 x 128] @ W(LDS)[128 -> 128]
__device__ __forceinline__ void gemm_regA(const bf16x8 a[4], const unsigned short* Wb,
                                          int m0, int kq, f32x4 acc[8]) {
  #pragma unroll
  for (int kk = 0; kk < 4; ++kk) {
    const int k0 = kk * 32 + kq * 8;
    #pragma unroll
    for (int tc = 0; tc < 8; ++tc) {
      bf16x8 b = *(const bf16x8*)&Wb[swz(tc * 16 + m0, k0)];
      acc[tc] = __builtin_amdgcn_mfma_f32_16x16x32_bf16(a[kk], b, acc[tc], 0, 0, 0);
    }
  }
}

// acc[8] += A(LDS rows wrow..wrow+16) @ W(LDS)
__device__ __forceinline__ void gemm_ldsA(const unsigned short* Hb, int wrow,
                                          const unsigned short* Wb,
                                          int m0, int kq, f32x4 acc[8]) {
  #pragma unroll
  for (int kk = 0; kk < 4; ++kk) {
    const int k0 = kk * 32 + kq * 8;
    bf16x8 a = *(const bf16x8*)&Hb[swz(wrow + m0, k0)];
    #pragma unroll
    for (int tc = 0; tc < 8; ++tc) {
      bf16x8 b = *(const bf16x8*)&Wb[swz(tc * 16 + m0, k0)];
      acc[tc] = __builtin_amdgcn_mfma_f32_16x16x32_bf16(a, b, acc[tc], 0, 0, 0);
    }
  }
}

__device__ __forceinline__ void zero_acc(f32x4 acc[8]) {
  #pragma unroll
  for (int b = 0; b < 8; ++b) acc[b] = (f32x4){0.f, 0.f, 0.f, 0.f};
}

// C-layout: col = tc*16 + (lane&15), row(within wave tile) = kq*4 + i
__device__ __forceinline__ void write_h(unsigned short* Hb, const f32x4 acc[8],
                                        const float* __restrict__ bias,
                                        int wrow, int m0, int kq) {
  #pragma unroll
  for (int tc = 0; tc < 8; ++tc) {
    const int col = tc * 16 + m0;
    const float b = bias[col];
    #pragma unroll
    for (int i = 0; i < 4; ++i)
      Hb[swz(wrow + kq * 4 + i, col)] = f2bf(fmaxf(acc[tc][i] + b, 0.0f));
  }
}

__device__ __forceinline__ void ln4(const f32x4 acc[8], float mu[4], float rv[4]) {
  float s[4] = {0, 0, 0, 0}, ss[4] = {0, 0, 0, 0};
  #pragma unroll
  for (int tc = 0; tc < 8; ++tc)
    #pragma unroll
    for (int i = 0; i < 4; ++i) {
      const float v = acc[tc][i];
      s[i] += v;
      ss[i] += v * v;
    }
  #pragma unroll
  for (int off = 1; off < 16; off <<= 1)
    #pragma unroll
    for (int i = 0; i < 4; ++i) {
      s[i] += __shfl_xor(s[i], off);
      ss[i] += __shfl_xor(ss[i], off);
    }
  #pragma unroll
  for (int i = 0; i < 4; ++i) {
    const float m = s[i] * (1.0f / 128.0f);
    const float var = ss[i] * (1.0f / 128.0f) - m * m;
    mu[i] = m;
    rv[i] = rsqrtf(var + EPS);
  }
}

// ---------------- prep kernels ----------------

__global__ void xprep_kernel(const float* __restrict__ x,
                             unsigned short* __restrict__ xb) {
  const long i = (long)blockIdx.x * 256 + threadIdx.x;
  const long base = i * 8;
  if (base < (long)N_NODES * H) {
    float4 v0 = *(const float4*)(x + base);
    float4 v1 = *(const float4*)(x + base + 4);
    PK8 pk;
    pk.u[0] = f2bf(v0.x); pk.u[1] = f2bf(v0.y);
    pk.u[2] = f2bf(v0.z); pk.u[3] = f2bf(v0.w);
    pk.u[4] = f2bf(v1.x); pk.u[5] = f2bf(v1.y);
    pk.u[6] = f2bf(v1.z); pk.u[7] = f2bf(v1.w);
    *(uint4*)(xb + base) = pk.q;
  }
}

struct WSrc { const float* p[9]; };

// Pre-swizzled LDS image: wimg[m*16384 + swz(n,k)] = W_m[k][n] (bf16)
__global__ void wprep_kernel(WSrc wsrc, unsigned short* __restrict__ wimg) {
  const int id = blockIdx.x * 256 + threadIdx.x;  // 9*16384
  const int m = id >> 14;
  const int r = id & 16383;
  const int n = r & 127;
  const int k = r >> 7;
  wimg[m * 16384 + swz(n, k)] = f2bf(wsrc.p[m][k * 128 + n]);
}

// ---------------- CSR build ----------------

__global__ void hist_kernel(const int* __restrict__ ridx, unsigned* __restrict__ cnt) {
  const int e = blockIdx.x * 256 + threadIdx.x;
  if (e < N_EDGES) atomicAdd(&cnt[ridx[e]], 1u);
}

__global__ void scan1_kernel(const unsigned* __restrict__ cnt,
                             unsigned* __restrict__ offs,
                             unsigned* __restrict__ part) {
  __shared__ unsigned sh[256];
  const int t = threadIdx.x;
  const int base = blockIdx.x * 1024 + t * 4;
  unsigned v[4];
  #pragma unroll
  for (int i = 0; i < 4; ++i) v[i] = (base + i < N_NODES) ? cnt[base + i] : 0u;
  unsigned pre[4];
  pre[0] = 0; pre[1] = v[0]; pre[2] = v[0] + v[1]; pre[3] = pre[2] + v[2];
  const unsigned tot = pre[3] + v[3];
  sh[t] = tot;
  __syncthreads();
  for (int d = 1; d < 256; d <<= 1) {
    const unsigned u_ = (t >= d) ? sh[t - d] : 0u;
    __syncthreads();
    sh[t] += u_;
    __syncthreads();
  }
  const unsigned excl = sh[t] - tot;
  #pragma unroll
  for (int i = 0; i < 4; ++i)
    if (base + i < N_NODES) offs[base + i] = excl + pre[i];
  if (t == 255) part[blockIdx.x] = sh[255];
}

__global__ void scan2_kernel(unsigned* __restrict__ part, int n) {
  __shared__ unsigned sh[128];
  const int t = threadIdx.x;
  const unsigned v = (t < n) ? part[t] : 0u;
  sh[t] = v;
  __syncthreads();
  for (int d = 1; d < 128; d <<= 1) {
    const unsigned u_ = (t >= d) ? sh[t - d] : 0u;
    __syncthreads();
    sh[t] += u_;
    __syncthreads();
  }
  if (t < n) part[t] = sh[t] - v;
}

__global__ void scan3_kernel(unsigned* __restrict__ offs,
                             const unsigned* __restrict__ part,
                             unsigned* __restrict__ cursor) {
  const int i = blockIdx.x * 256 + threadIdx.x;
  if (i < N_NODES) {
    const unsigned o = offs[i] + part[i >> 10];
    offs[i] = o;
    cursor[i] = o;
  }
  if (i == 0) offs[N_NODES] = N_EDGES;
}

__global__ void scatter_kernel(const int* __restrict__ ridx,
                               unsigned* __restrict__ cursor,
                               unsigned* __restrict__ eord) {
  const int e = blockIdx.x * 256 + threadIdx.x;
  if (e < N_EDGES) {
    const unsigned p = atomicAdd(&cursor[ridx[e]], 1u);
    eord[p] = (unsigned)e;
  }
}

// ---------------- main kernels ----------------

__global__ __launch_bounds__(512, 4) void edge_kernel(
    const unsigned short* __restrict__ xb, const float* __restrict__ edge_attr,
    const int* __restrict__ eidx, const unsigned short* __restrict__ wimg,
    const float* __restrict__ eb1, const float* __restrict__ eb2,
    const float* __restrict__ eb3,
    const float* __restrict__ eg, const float* __restrict__ ebeta,
    float* __restrict__ out_e, unsigned short* __restrict__ enew) {
  __shared__ unsigned short Wbuf[128 * 128];
  __shared__ unsigned short Hbuf[128 * 128];

  const int t = threadIdx.x;
  const int lane = t & 63;
  const int wave = t >> 6;
  const int wrow = wave * 16;
  const int m0 = lane & 15;
  const int kq = lane >> 4;
  const long e0 = (long)blockIdx.x * 128;
  const int* sidx = eidx;
  const int* ridx = eidx + N_EDGES;

  // t0: stage W1a->Wbuf, W1b->Hbuf (Hbuf free during layer 1)
  stage_w512(Wbuf, wimg + 0L * 16384);
  stage_w512(Hbuf, wimg + 1L * 16384);

  // t0: gather A fragments straight to registers
  long erow = e0 + wrow + m0;
  if (erow > N_EDGES - 1) erow = N_EDGES - 1;
  const long ns = sidx[erow];
  const long nr = ridx[erow];
  bf16x8 aS[4], aR[4];
  {
    const unsigned short* ps = xb + ns * H + kq * 8;
    const unsigned short* pr = xb + nr * H + kq * 8;
    #pragma unroll
    for (int kk = 0; kk < 4; ++kk) {
      aS[kk] = *(const bf16x8*)(ps + kk * 32);
      aR[kk] = *(const bf16x8*)(pr + kk * 32);
    }
  }

  f32x4 acc[8];
  zero_acc(acc);

  __syncthreads();  // W1a, W1b staged
  gemm_regA(aS, Wbuf, m0, kq, acc);
  gemm_regA(aR, Hbuf, m0, kq, acc);

  // edge_attr fragments (f32 -> bf16), loads issued here, used after next sync
  bf16x8 aE[4];
  {
    const float* pe = edge_attr + erow * (long)H + kq * 8;
    #pragma unroll
    for (int kk = 0; kk < 4; ++kk) {
      float4 v0 = *(const float4*)(pe + kk * 32);
      float4 v1 = *(const float4*)(pe + kk * 32 + 4);
      PK8 pk;
      pk.u[0] = f2bf(v0.x); pk.u[1] = f2bf(v0.y);
      pk.u[2] = f2bf(v0.z); pk.u[3] = f2bf(v0.w);
      pk.u[4] = f2bf(v1.x); pk.u[5] = f2bf(v1.y);
      pk.u[6] = f2bf(v1.z); pk.u[7] = f2bf(v1.w);
      aE[kk] = __builtin_bit_cast(bf16x8, pk.q);
    }
  }

  __syncthreads();  // all waves done with Wbuf (W1a)
  stage_w512(Wbuf, wimg + 2L * 16384);  // W1c
  __syncthreads();
  gemm_regA(aE, Wbuf, m0, kq, acc);

  __syncthreads();  // Wbuf (W1c) consumed; Hbuf (W1b) long consumed
  stage_w512(Wbuf, wimg + 3L * 16384);  // W2
  write_h(Hbuf, acc, eb1, wrow, m0, kq);  // h1
  zero_acc(acc);
  __syncthreads();
  gemm_ldsA(Hbuf, wrow, Wbuf, m0, kq, acc);

  __syncthreads();
  stage_w512(Wbuf, wimg + 4L * 16384);  // W3
  write_h(Hbuf, acc, eb2, wrow, m0, kq);  // h2
  zero_acc(acc);
  __syncthreads();
  gemm_ldsA(Hbuf, wrow, Wbuf, m0, kq, acc);

  // ---- epilogue: +b3, LN ----
  float gm[8], bt[8];
  #pragma unroll
  for (int tc = 0; tc < 8; ++tc) {
    const int col = tc * 16 + m0;
    const float b3 = eb3[col];
    gm[tc] = eg[col];
    bt[tc] = ebeta[col];
    #pragma unroll
    for (int i = 0; i < 4; ++i) acc[tc][i] += b3;
  }
  float mu[4], rv[4];
  ln4(acc, mu, rv);

  __syncthreads();  // Hbuf (h2) consumed by all waves
  #pragma unroll
  for (int tc = 0; tc < 8; ++tc) {
    const int col = tc * 16 + m0;
    #pragma unroll
    for (int i = 0; i < 4; ++i) {
      const float y = (acc[tc][i] - mu[i]) * rv[i] * gm[tc] + bt[tc];
      Hbuf[swz(wrow + kq * 4 + i, col)] = f2bf(y);
    }
  }
  __syncthreads();

  // coalesced stores: 4 threads per row, 32 cols each
  {
    const int r = t >> 2;
    const int c0 = (t & 3) * 32;
    const long e = e0 + r;
    if (e < N_EDGES) {
      const float* ea = edge_attr + e * (long)H + c0;
      float* oe = out_e + e * (long)H + c0;
      unsigned short* en = enew + e * (long)H + c0;
      #pragma unroll
      for (int c2 = 0; c2 < 4; ++c2) {
        uint4 qv = *(const uint4*)&Hbuf[swz(r, c0 + c2 * 8)];
        *(uint4*)(en + c2 * 8) = qv;
        const unsigned short* pu = (const unsigned short*)&qv;
        float4 a0 = *(const float4*)(ea + c2 * 8);
        float4 a1 = *(const float4*)(ea + c2 * 8 + 4);
        float4 o0, o1;
        o0.x = a0.x + bf2f(pu[0]); o0.y = a0.y + bf2f(pu[1]);
        o0.z = a0.z + bf2f(pu[2]); o0.w = a0.w + bf2f(pu[3]);
        o1.x = a1.x + bf2f(pu[4]); o1.y = a1.y + bf2f(pu[5]);
        o1.z = a1.z + bf2f(pu[6]); o1.w = a1.w + bf2f(pu[7]);
        *(float4*)(oe + c2 * 8) = o0;
        *(float4*)(oe + c2 * 8 + 4) = o1;
      }
    }
  }
}

__global__ __launch_bounds__(512, 4) void node_kernel(
    const unsigned short* __restrict__ xb, const float* __restrict__ x,
    const unsigned short* __restrict__ enew,
    const unsigned* __restrict__ offs, const unsigned* __restrict__ eord,
    const unsigned short* __restrict__ wimg,
    const float* __restrict__ nb1, const float* __restrict__ nb2,
    const float* __restrict__ nb3,
    const float* __restrict__ ng, const float* __restrict__ nbeta,
    float* __restrict__ out_x) {
  __shared__ unsigned short Wbuf[128 * 128];
  __shared__ unsigned short Hbuf[128 * 128];

  const int t = threadIdx.x;
  const int lane = t & 63;
  const int wave = t >> 6;
  const int wrow = wave * 16;
  const int m0 = lane & 15;
  const int kq = lane >> 4;
  const long n0 = (long)blockIdx.x * 128;

  stage_w512(Wbuf, wimg + 5L * 16384);  // nW1a

  // x fragments to registers
  long nrow = n0 + wrow + m0;
  if (nrow > N_NODES - 1) nrow = N_NODES - 1;
  bf16x8 aX[4];
  {
    const unsigned short* px = xb + nrow * H + kq * 8;
    #pragma unroll
    for (int kk = 0; kk < 4; ++kk) aX[kk] = *(const bf16x8*)(px + kk * 32);
  }

  // CSR gather-sum: thread t owns (row t>>2, col quarter t&3)
  float av[32];
  #pragma unroll
  for (int i = 0; i < 32; ++i) av[i] = 0.f;
  {
    const long sn = n0 + (t >> 2);
    if (sn < N_NODES) {
      const unsigned o0 = offs[sn], o1 = offs[sn + 1];
      const int c0 = (t & 3) * 32;
      for (unsigned u_ = o0; u_ < o1; ++u_) {
        const unsigned short* er = enew + (long)eord[u_] * H + c0;
        #pragma unroll
        for (int c2 = 0; c2 < 4; ++c2) {
          uint4 qv = *(const uint4*)(er + c2 * 8);
          const unsigned short* pu = (const unsigned short*)&qv;
          #pragma unroll
          for (int j = 0; j < 8; ++j) av[c2 * 8 + j] += bf2f(pu[j]);
        }
      }
    }
  }

  f32x4 acc[8];
  zero_acc(acc);

  __syncthreads();  // Wbuf staged
  gemm_regA(aX, Wbuf, m0, kq, acc);
  __syncthreads();
  stage_w512(Wbuf, wimg + 6L * 16384);  // nW1b
  // av -> Hbuf (bf16, swizzled)
  {
    const int r = t >> 2;
    const int c0 = (t & 3) * 32;
    #pragma unroll
    for (int c2 = 0; c2 < 4; ++c2) {
      PK8 pk;
      #pragma unroll
      for (int j = 0; j < 8; ++j) pk.u[j] = f2bf(av[c2 * 8 + j]);
      *(uint4*)&Hbuf[swz(r, c0 + c2 * 8)] = pk.q;
    }
  }
  __syncthreads();
  gemm_ldsA(Hbuf, wrow, Wbuf, m0, kq, acc);  // acc += agg @ nW1b

  __syncthreads();
  stage_w512(Wbuf, wimg + 7L * 16384);  // nW2
  write_h(Hbuf, acc, nb1, wrow, m0, kq);
  zero_acc(acc);
  __syncthreads();
  gemm_ldsA(Hbuf, wrow, Wbuf, m0, kq, acc);

  __syncthreads();
  stage_w512(Wbuf, wimg + 8L * 16384);  // nW3
  write_h(Hbuf, acc, nb2, wrow, m0, kq);
  zero_acc(acc);
  __syncthreads();
  gemm_ldsA(Hbuf, wrow, Wbuf, m0, kq, acc);

  // epilogue
  float gm[8], bt[8];
  #pragma unroll
  for (int tc = 0; tc < 8; ++tc) {
    const int col = tc * 16 + m0;
    const float b3 = nb3[col];
    gm[tc] = ng[col];
    bt[tc] = nbeta[col];
    #pragma unroll
    for (int i = 0; i < 4; ++i) acc[tc][i] += b3;
  }
  float mu[4], rv[4];
  ln4(acc, mu, rv);

  __syncthreads();
  #pragma unroll
  for (int tc = 0; tc < 8; ++tc) {
    const int col = tc * 16 + m0;
    #pragma unroll
    for (int i = 0; i < 4; ++i) {
      const float y = (acc[tc][i] - mu[i]) * rv[i] * gm[tc] + bt[tc];
      Hbuf[swz(wrow + kq * 4 + i, col)] = f2bf(y);
    }
  }
  __syncthreads();

  {
    const int r = t >> 2;
    const int c0 = (t & 3) * 32;
    const long n = n0 + r;
    if (n < N_NODES) {
      const float* xr = x + n * (long)H + c0;
      float* ox = out_x + n * (long)H + c0;
      #pragma unroll
      for (int c2 = 0; c2 < 4; ++c2) {
        uint4 qv = *(const uint4*)&Hbuf[swz(r, c0 + c2 * 8)];
        const unsigned short* pu = (const unsigned short*)&qv;
        float4 a0 = *(const float4*)(xr + c2 * 8);
        float4 a1 = *(const float4*)(xr + c2 * 8 + 4);
        float4 o0, o1;
        o0.x = a0.x + bf2f(pu[0]); o0.y = a0.y + bf2f(pu[1]);
        o0.z = a0.z + bf2f(pu[2]); o0.w = a0.w + bf2f(pu[3]);
        o1.x = a1.x + bf2f(pu[4]); o1.y = a1.y + bf2f(pu[5]);
        o1.z = a1.z + bf2f(pu[6]); o1.w = a1.w + bf2f(pu[7]);
        *(float4*)(ox + c2 * 8) = o0;
        *(float4*)(ox + c2 * 8 + 4) = o1;
      }
    }
  }
}

extern "C" void kernel_launch(void* const* d_in, const int* in_sizes, int n_in,
                              void* d_out, int out_size, void* d_ws, size_t ws_size,
                              hipStream_t stream) {
  (void)in_sizes; (void)n_in; (void)out_size; (void)ws_size;
  const float* x         = (const float*)d_in[0];
  const float* edge_attr = (const float*)d_in[1];
  const int*   eidx      = (const int*)d_in[2];
  const float* eW1 = (const float*)d_in[3];
  const float* eb1 = (const float*)d_in[4];
  const float* eW2 = (const float*)d_in[5];
  const float* eb2 = (const float*)d_in[6];
  const float* eW3 = (const float*)d_in[7];
  const float* eb3 = (const float*)d_in[8];
  const float* eg  = (const float*)d_in[9];
  const float* ebt = (const float*)d_in[10];
  const float* nW1 = (const float*)d_in[11];
  const float* nb1 = (const float*)d_in[12];
  const float* nW2 = (const float*)d_in[13];
  const float* nb2 = (const float*)d_in[14];
  const float* nW3 = (const float*)d_in[15];
  const float* nb3 = (const float*)d_in[16];
  const float* ng  = (const float*)d_in[17];
  const float* nbt = (const float*)d_in[18];

  float* out_x = (float*)d_out;                        // N_NODES*H
  float* out_e = (float*)d_out + (size_t)N_NODES * H;  // N_EDGES*H

  // ws layout (bytes)
  char* w = (char*)d_ws;
  unsigned short* enew = (unsigned short*)(w + 0);            // 128,000,000
  unsigned short* xb   = (unsigned short*)(w + 128000000);    //  25,600,000
  unsigned short* wimg = (unsigned short*)(w + 153600000);    //     294,912
  unsigned* offs   = (unsigned*)(w + 153894912);              //     400,128
  unsigned* cnt    = (unsigned*)(w + 154295040);              //     400,128
  unsigned* cursor = (unsigned*)(w + 154695168);              //     400,128
  unsigned* part   = (unsigned*)(w + 155095296);              //       1,024
  unsigned* eord   = (unsigned*)(w + 155096320);              //   2,000,000
  // total ~157.1 MB

  const int* ridx = eidx + N_EDGES;

  hipMemsetAsync(cnt, 0, (size_t)N_NODES * sizeof(unsigned), stream);

  WSrc wsrc;
  wsrc.p[0] = eW1;
  wsrc.p[1] = eW1 + 16384;
  wsrc.p[2] = eW1 + 32768;
  wsrc.p[3] = eW2;
  wsrc.p[4] = eW3;
  wsrc.p[5] = nW1;
  wsrc.p[6] = nW1 + 16384;
  wsrc.p[7] = nW2;
  wsrc.p[8] = nW3;

  xprep_kernel<<<(N_NODES * H / 8 + 255) / 256, 256, 0, stream>>>(x, xb);
  wprep_kernel<<<576, 256, 0, stream>>>(wsrc, wimg);

  hist_kernel<<<(N_EDGES + 255) / 256, 256, 0, stream>>>(ridx, cnt);
  scan1_kernel<<<(N_NODES + 1023) / 1024, 256, 0, stream>>>(cnt, offs, part);
  scan2_kernel<<<1, 128, 0, stream>>>(part, (N_NODES + 1023) / 1024);
  scan3_kernel<<<(N_NODES + 255) / 256, 256, 0, stream>>>(offs, part, cursor);
  scatter_kernel<<<(N_EDGES + 255) / 256, 256, 0, stream>>>(ridx, cursor, eord);

  const int eblocks = (N_EDGES + 127) / 128;  // 3907
  const int nblocks = (N_NODES + 127) / 128;  // 782
  edge_kernel<<<eblocks, 512, 0, stream>>>(xb, edge_attr, eidx, wimg, eb1, eb2, eb3,
                                           eg, ebt, out_e, enew);
  node_kernel<<<nblocks, 512, 0, stream>>>(xb, x, enew, offs, eord, wimg,
                                           nb1, nb2, nb3, ng, nbt, out_x);
}